// Round 6
// baseline (145.074 us; speedup 1.0000x reference)
//
#include <hip/hip_runtime.h>

#define B_    64
#define C_    23
#define E_    1024
#define D_    1024
#define BOT_  128
#define BINS_ 8192
#define S_    3
#define NUMBINS (C_*BINS_)

typedef float f32x4 __attribute__((ext_vector_type(4)));

// ws layout (floats):
// [0,384)            M  : M[s*128+k]   = sum_d Wfc[s][d]      * Wb[d][k]
// [512,512+3072)     N  : N[s*1024+e]  = sum_d Wfc[s][1024+d] * We[d][e]
// [3584,3587)        c0 : c0[s]
// [3590]             pe_done counter (uint, zeroed by kprep each launch)
// [3600,3600+4416)   pe : pe[(b*C+c)*3+s]
#define WS_M   0
#define WS_N   512
#define WS_C0  3584
#define WS_CNT 3590
#define WS_PE  3600

// grid 73: [0,64): N (e0 = bx*16, all 3 s)  [64,72): M (k0=(bx-64)*16)  72: c0+cnt
__global__ __launch_bounds__(256) void kprep(const float* __restrict__ Wb,
                                             const float* __restrict__ We,
                                             const float* __restrict__ be,
                                             const float* __restrict__ Wfc,
                                             const float* __restrict__ bfc,
                                             float* __restrict__ ws) {
    const int bx = blockIdx.x;
    const int t  = threadIdx.x;

    if (bx == 72) {                // c0 + counter reset
        if (t == 0) *(volatile unsigned*)(ws + WS_CNT) = 0u;
        int wave = t >> 6, lane = t & 63;
        if (wave < 3) {
            const float* w2 = Wfc + wave * 2 * D_ + D_;
            float acc = 0.f;
            #pragma unroll
            for (int j = 0; j < D_ / 64; j++) {
                int d = lane + j * 64;
                acc += w2[d] * be[d];
            }
            #pragma unroll
            for (int off = 32; off; off >>= 1) acc += __shfl_down(acc, off);
            if (lane == 0) ws[WS_C0 + wave] = acc + bfc[wave];
        }
        return;
    }

    __shared__ float wv[3072];     // 3 broadcast rows of Wfc (w1 or w2)
    __shared__ float red[256];

    const int og   = t & 15;       // output within the 16-chunk
    const int dgrp = t >> 4;       // 0..15, each owns 64 d's

    const float* src;              // matrix: src[d*ostride + obase + og]
    int ostride, obase, wofs;
    float* dst0;                   // + s*dstride
    int dstride;

    if (bx < 64) {                 // N[s][e0+og]
        int e0 = bx * 16;
        src = We; ostride = E_; obase = e0; wofs = D_;
        dst0 = ws + WS_N + e0; dstride = E_;
    } else {                       // M[s][k0+og]
        int k0 = (bx - 64) * 16;
        src = Wb; ostride = BOT_; obase = k0; wofs = 0;
        dst0 = ws + WS_M + k0; dstride = BOT_;
    }

    for (int i = t; i < 3072; i += 256) {
        int s = i >> 10, d = i & 1023;
        wv[i] = Wfc[s * 2 * D_ + wofs + d];
    }
    __syncthreads();

    const float* p  = src + (size_t)(dgrp * 64) * ostride + obase + og;
    const float* w0 = wv + dgrp * 64;
    float a0 = 0.f, a1 = 0.f, a2 = 0.f;
    #pragma unroll 8
    for (int i = 0; i < 64; i++) {
        float v = p[(size_t)i * ostride];
        a0 += w0[i] * v;
        a1 += w0[1024 + i] * v;
        a2 += w0[2048 + i] * v;
    }
    float accs[3] = {a0, a1, a2};
    for (int s = 0; s < 3; s++) {
        __syncthreads();
        red[t] = accs[s];
        #pragma unroll
        for (int off = 128; off >= 16; off >>= 1) {
            __syncthreads();
            if (t < off) red[t] += red[t + off];
        }
        if (t < 16) dst0[s * dstride + t] = red[t];
    }
}

// grid 736 (= (c=bid>>5, n0=(bid&31)*256)), 256 thr, 28 KB LDS -> 5 blocks/CU
// => 1280 resident slots >= 736: ALL blocks co-resident, spin is deadlock-free
// and schedule-independent.
// phase 0: waves 0,1 compute pe rows 2*bid,2*bid+1; release-atomicAdd counter.
// phase 1: R4's coalesced table reads -> padded-LDS partials -> pbl.
// spin (acquire) for counter==1472, then phase 2 write streaming.
__global__ __launch_bounds__(256) void kmainf(const float* __restrict__ table,
                                              const float* __restrict__ eos,
                                              float* __restrict__ ws,
                                              float* __restrict__ out) {
    const int t   = threadIdx.x;
    const int bid = blockIdx.x;
    const int c   = bid >> 5;
    const int n0  = (bid & 31) * 256;

    const int w  = t >> 6;         // wave 0..3
    const int l  = t & 63;
    const int h  = l >> 5;         // row parity within pair
    const int kk = l & 31;         // f32x4 quad within row

    __shared__ float P[64 * 97];   // partials, padded stride 97
    __shared__ float pbl[768];     // pb[n_local*3+s]
    __shared__ float pel[192];     // pe[b*3+s] for this c

    unsigned* cnt = (unsigned*)(ws + WS_CNT);

    // per-lane M coefficients: M[s][kk*4 .. kk*4+3]
    f32x4 M0 = ((const f32x4*)(ws + WS_M      ))[kk];
    f32x4 M1 = ((const f32x4*)(ws + WS_M + 128))[kk];
    f32x4 M2 = ((const f32x4*)(ws + WS_M + 256))[kk];

    const float* base = table + (size_t)(1 + c * BINS_ + n0) * BOT_ + kk * 4;

    // issue batch-0 table loads FIRST (critical path), pe math hides under them
    f32x4 va[8], vb[8];
    #pragma unroll
    for (int i = 0; i < 8; i++) {
        int rl = (w * 8 + i) * 2 + h;
        va[i] = *(const f32x4*)(base + (size_t)rl * BOT_);
    }

    // phase 0: pe rows 2*bid + w  (waves 0,1)
    if (w < 2) {
        int row = 2 * bid + w;
        const f32x4* x  = (const f32x4*)(eos + (size_t)row * E_);
        const f32x4* Nq = (const f32x4*)(ws + WS_N);
        float a0 = 0.f, a1 = 0.f, a2 = 0.f;
        #pragma unroll
        for (int j = 0; j < 4; j++) {
            int q = l + 64 * j;
            f32x4 v  = x[q];
            f32x4 q0 = Nq[q], q1 = Nq[256 + q], q2 = Nq[512 + q];
            a0 += v.x * q0.x + v.y * q0.y + v.z * q0.z + v.w * q0.w;
            a1 += v.x * q1.x + v.y * q1.y + v.z * q1.z + v.w * q1.w;
            a2 += v.x * q2.x + v.y * q2.y + v.z * q2.z + v.w * q2.w;
        }
        #pragma unroll
        for (int mask = 32; mask; mask >>= 1) {
            a0 += __shfl_xor(a0, mask);
            a1 += __shfl_xor(a1, mask);
            a2 += __shfl_xor(a2, mask);
        }
        if (l == 0) {
            float* pe = ws + WS_PE + row * 3;
            pe[0] = a0 + ws[WS_C0 + 0];
            pe[1] = a1 + ws[WS_C0 + 1];
            pe[2] = a2 + ws[WS_C0 + 2];
            __hip_atomic_fetch_add(cnt, 1u, __ATOMIC_RELEASE, __HIP_MEMORY_SCOPE_AGENT);
        }
    }

    // phase 1: 4 batches of 64 rows, register double-buffer
    #pragma unroll
    for (int bb = 0; bb < 4; bb++) {
        #pragma unroll
        for (int i = 0; i < 8; i++) {
            int rl = (w * 8 + i) * 2 + h;
            f32x4 v = (bb & 1) ? vb[i] : va[i];
            float* pp = &P[rl * 97 + kk * 3];
            pp[0] = v.x * M0.x + v.y * M0.y + v.z * M0.z + v.w * M0.w;
            pp[1] = v.x * M1.x + v.y * M1.y + v.z * M1.z + v.w * M1.w;
            pp[2] = v.x * M2.x + v.y * M2.y + v.z * M2.z + v.w * M2.w;
        }
        if (bb < 3) {
            #pragma unroll
            for (int i = 0; i < 8; i++) {
                int rl = (w * 8 + i) * 2 + h;
                f32x4 ld = *(const f32x4*)(base + (size_t)((bb + 1) * 64 + rl) * BOT_);
                if (bb & 1) va[i] = ld; else vb[i] = ld;
            }
        }
        __syncthreads();
        if (t < 192) {
            int s = t >> 6, ro = t & 63;
            const float* pr = &P[ro * 97 + s];
            float acc = 0.f;
            #pragma unroll
            for (int k = 0; k < 32; k++) acc += pr[k * 3];
            pbl[(bb * 64 + ro) * 3 + s] = acc;
        }
        __syncthreads();
    }

    // wait for all 1472 pe rows (nearly always already done)
    while (__hip_atomic_load(cnt, __ATOMIC_ACQUIRE, __HIP_MEMORY_SCOPE_AGENT) < 1472u)
        __builtin_amdgcn_s_sleep(2);

    if (t < 192) {
        int b = t / 3, s = t - b * 3;
        pel[t] = ws[WS_PE + (b * C_ + c) * 3 + s];
    }
    __syncthreads();

    // phase 2: for each b, write relu(pb + pe) as contiguous float4s
    if (t < 192) {
        f32x4 pv = *(const f32x4*)&pbl[t * 4];
        int s0 = t % 3;                 // (4t)%3 == t%3
        int s1 = (s0 + 1 == 3) ? 0 : s0 + 1;
        int s2 = (s1 + 1 == 3) ? 0 : s1 + 1;
        for (int b = 0; b < B_; b++) {
            const float* pe = &pel[b * 3];
            f32x4 o;
            o.x = fmaxf(pv.x + pe[s0], 0.f);
            o.y = fmaxf(pv.y + pe[s1], 0.f);
            o.z = fmaxf(pv.z + pe[s2], 0.f);
            o.w = fmaxf(pv.w + pe[s0], 0.f);
            f32x4* dst = (f32x4*)(out + ((size_t)(b * C_ + c) * BINS_ + n0) * 3) + t;
            __builtin_nontemporal_store(o, dst);
        }
    }
}

extern "C" void kernel_launch(void* const* d_in, const int* in_sizes, int n_in,
                              void* d_out, int out_size, void* d_ws, size_t ws_size,
                              hipStream_t stream) {
    const float* eos   = (const float*)d_in[0];
    const float* table = (const float*)d_in[1];
    const float* Wb    = (const float*)d_in[2];
    const float* We    = (const float*)d_in[3];
    const float* be    = (const float*)d_in[4];
    const float* Wfc   = (const float*)d_in[5];
    const float* bfc   = (const float*)d_in[6];
    float* out = (float*)d_out;
    float* ws  = (float*)d_ws;

    kprep<<<73, 256, 0, stream>>>(Wb, We, be, Wfc, bfc, ws);
    kmainf<<<736, 256, 0, stream>>>(table, eos, ws, out);
}

// Round 7
// 51.664 us; speedup vs baseline: 2.8080x; 2.8080x over previous
//
#include <hip/hip_runtime.h>

#define B_    64
#define C_    23
#define E_    1024
#define D_    1024
#define BOT_  128
#define BINS_ 8192
#define S_    3
#define NUMBINS (C_*BINS_)

typedef float f32x4 __attribute__((ext_vector_type(4)));

// ws layout (floats):
// [0,384)            M  : M[s*128+k]   = sum_d Wfc[s][d]      * Wb[d][k]
// [512,512+3072)     N  : N[s*1024+e]  = sum_d Wfc[s][1024+d] * We[d][e]
// [3584,3587)        c0 : c0[s]
// [3600,3600+4416)   pe : pe[(b*C+c)*3+s]
#define WS_M   0
#define WS_N   512
#define WS_C0  3584
#define WS_PE  3600

// grid 73: [0,64): N (e0 = bx*16, all 3 s)  [64,72): M (k0=(bx-64)*16)  72: c0
__global__ __launch_bounds__(256) void kprep(const float* __restrict__ Wb,
                                             const float* __restrict__ We,
                                             const float* __restrict__ be,
                                             const float* __restrict__ Wfc,
                                             const float* __restrict__ bfc,
                                             float* __restrict__ ws) {
    const int bx = blockIdx.x;
    const int t  = threadIdx.x;

    if (bx == 72) {                // c0
        int wave = t >> 6, lane = t & 63;
        if (wave < 3) {
            const float* w2 = Wfc + wave * 2 * D_ + D_;
            float acc = 0.f;
            #pragma unroll
            for (int j = 0; j < D_ / 64; j++) {
                int d = lane + j * 64;
                acc += w2[d] * be[d];
            }
            #pragma unroll
            for (int off = 32; off; off >>= 1) acc += __shfl_down(acc, off);
            if (lane == 0) ws[WS_C0 + wave] = acc + bfc[wave];
        }
        return;
    }

    __shared__ float wv[3072];     // 3 broadcast rows of Wfc (w1 or w2)
    __shared__ float red[256];

    const int og   = t & 15;       // output within the 16-chunk
    const int dgrp = t >> 4;       // 0..15, each owns 64 d's

    const float* src;              // matrix: src[d*ostride + obase + og]
    int ostride, obase, wofs;
    float* dst0;                   // + s*dstride
    int dstride;

    if (bx < 64) {                 // N[s][e0+og]
        int e0 = bx * 16;
        src = We; ostride = E_; obase = e0; wofs = D_;
        dst0 = ws + WS_N + e0; dstride = E_;
    } else {                       // M[s][k0+og]
        int k0 = (bx - 64) * 16;
        src = Wb; ostride = BOT_; obase = k0; wofs = 0;
        dst0 = ws + WS_M + k0; dstride = BOT_;
    }

    for (int i = t; i < 3072; i += 256) {
        int s = i >> 10, d = i & 1023;
        wv[i] = Wfc[s * 2 * D_ + wofs + d];
    }
    __syncthreads();

    const float* p  = src + (size_t)(dgrp * 64) * ostride + obase + og;
    const float* w0 = wv + dgrp * 64;
    float a0 = 0.f, a1 = 0.f, a2 = 0.f;
    #pragma unroll 8
    for (int i = 0; i < 64; i++) {
        float v = p[(size_t)i * ostride];
        a0 += w0[i] * v;
        a1 += w0[1024 + i] * v;
        a2 += w0[2048 + i] * v;
    }
    float accs[3] = {a0, a1, a2};
    for (int s = 0; s < 3; s++) {
        __syncthreads();
        red[t] = accs[s];
        #pragma unroll
        for (int off = 128; off >= 16; off >>= 1) {
            __syncthreads();
            if (t < off) red[t] += red[t + off];
        }
        if (t < 16) dst0[s * dstride + t] = red[t];
    }
}

// one wave per (b,c) row: pe = eos_emb[row]·N[s] + c0[s]
__global__ __launch_bounds__(256) void kpe(const float* __restrict__ eos,
                                           float* ws) {
    int wave = threadIdx.x >> 6;
    int lane = threadIdx.x & 63;
    int row  = blockIdx.x * 4 + wave;      // 0..B*C-1 (=1471)
    const float* x  = eos + (size_t)row * E_;
    const float* N0 = ws + WS_N;
    float a0 = 0.f, a1 = 0.f, a2 = 0.f;
    #pragma unroll
    for (int j = 0; j < E_ / 64; j++) {
        int i = lane + j * 64;
        float v = x[i];
        a0 += v * N0[i];
        a1 += v * N0[1024 + i];
        a2 += v * N0[2048 + i];
    }
    #pragma unroll
    for (int off = 32; off; off >>= 1) {
        a0 += __shfl_down(a0, off);
        a1 += __shfl_down(a1, off);
        a2 += __shfl_down(a2, off);
    }
    if (lane == 0) {
        float* pe = ws + WS_PE + row * 3;
        pe[0] = a0 + ws[WS_C0 + 0];
        pe[1] = a1 + ws[WS_C0 + 1];
        pe[2] = a2 + ws[WS_C0 + 2];
    }
}

// grid (32, 23): block = (c=blockIdx.y, n-chunk of 256 = blockIdx.x)
// Per 64-row batch: coalesced 1KB/instr table reads (reg double-buffer) ->
// padded-LDS partials -> reduce -> IMMEDIATELY stream this batch's 64-b
// output slice (12 x 256-thread NT f32x4 stores) while next batch's loads
// are in flight. Reads and writes overlap chip-wide for the whole kernel.
__global__ __launch_bounds__(256) void kmain(const float* __restrict__ table,
                                             const float* __restrict__ ws,
                                             float* __restrict__ out) {
    const int t  = threadIdx.x;
    const int c  = blockIdx.y;
    const int n0 = blockIdx.x * 256;

    const int w  = t >> 6;         // wave 0..3
    const int l  = t & 63;
    const int h  = l >> 5;         // row parity within pair
    const int kk = l & 31;         // f32x4 quad within row

    __shared__ float P[64 * 97];   // partials, padded stride 97 (conflict-free)
    __shared__ float pbl[192];     // this batch's pb[row_local*3+s]
    __shared__ float pel[192];     // pe[b*3+s] for this c

    // per-lane M coefficients: M[s][kk*4 .. kk*4+3]
    f32x4 M0 = ((const f32x4*)(ws + WS_M      ))[kk];
    f32x4 M1 = ((const f32x4*)(ws + WS_M + 128))[kk];
    f32x4 M2 = ((const f32x4*)(ws + WS_M + 256))[kk];

    if (t < 192) {
        int b = t / 3, s = t - b * 3;
        pel[t] = ws[WS_PE + (b * C_ + c) * 3 + s];
    }

    const float* base = table + (size_t)(1 + c * BINS_ + n0) * BOT_ + kk * 4;

    f32x4 va[8], vb[8];
    #pragma unroll
    for (int i = 0; i < 8; i++) {
        int rl = (w * 8 + i) * 2 + h;
        va[i] = *(const f32x4*)(base + (size_t)rl * BOT_);
    }

    #pragma unroll
    for (int bb = 0; bb < 4; bb++) {
        // partials for batch bb from the live register buffer
        #pragma unroll
        for (int i = 0; i < 8; i++) {
            int rl = (w * 8 + i) * 2 + h;
            f32x4 v = (bb & 1) ? vb[i] : va[i];
            float* pp = &P[rl * 97 + kk * 3];
            pp[0] = v.x * M0.x + v.y * M0.y + v.z * M0.z + v.w * M0.w;
            pp[1] = v.x * M1.x + v.y * M1.y + v.z * M1.z + v.w * M1.w;
            pp[2] = v.x * M2.x + v.y * M2.y + v.z * M2.z + v.w * M2.w;
        }
        // issue next batch's loads early (in flight across reduce + stores)
        if (bb < 3) {
            #pragma unroll
            for (int i = 0; i < 8; i++) {
                int rl = (w * 8 + i) * 2 + h;
                f32x4 ld = *(const f32x4*)(base + (size_t)((bb + 1) * 64 + rl) * BOT_);
                if (bb & 1) va[i] = ld; else vb[i] = ld;
            }
        }
        __syncthreads();
        // reduce: 192 threads, s = t>>6, local row = t&63
        if (t < 192) {
            int s = t >> 6, ro = t & 63;
            const float* pr = &P[ro * 97 + s];
            float acc = 0.f;
            #pragma unroll
            for (int k = 0; k < 32; k++) acc += pr[k * 3];
            pbl[ro * 3 + s] = acc;
        }
        __syncthreads();
        // stream this batch's outputs: 64 b-slices x 48 f32x4, all 256 threads.
        // flat f32x4 index q = t + 256*j; b = q/48, p4 = q%48 (incremental).
        {
            int b  = t / 48;
            int p4 = t - b * 48;
            const float* ob = out + ((size_t)c * BINS_ + n0 + bb * 64) * 3;
            #pragma unroll
            for (int j = 0; j < 12; j++) {
                f32x4 pv = *(const f32x4*)&pbl[p4 * 4];
                int s0 = p4 % 3;            // (4*p4)%3 == p4%3
                int s1 = (s0 + 1 == 3) ? 0 : s0 + 1;
                int s2 = (s1 + 1 == 3) ? 0 : s1 + 1;
                const float* pe = &pel[b * 3];
                f32x4 o;
                o.x = fmaxf(pv.x + pe[s0], 0.f);
                o.y = fmaxf(pv.y + pe[s1], 0.f);
                o.z = fmaxf(pv.z + pe[s2], 0.f);
                o.w = fmaxf(pv.w + pe[s0], 0.f);
                f32x4* dst = (f32x4*)(ob + (size_t)b * (C_ * BINS_ * 3)) + p4;
                __builtin_nontemporal_store(o, dst);
                b += 5; p4 += 16;           // q += 256 = 5*48 + 16
                if (p4 >= 48) { p4 -= 48; b += 1; }
            }
        }
    }
}

extern "C" void kernel_launch(void* const* d_in, const int* in_sizes, int n_in,
                              void* d_out, int out_size, void* d_ws, size_t ws_size,
                              hipStream_t stream) {
    const float* eos   = (const float*)d_in[0];
    const float* table = (const float*)d_in[1];
    const float* Wb    = (const float*)d_in[2];
    const float* We    = (const float*)d_in[3];
    const float* be    = (const float*)d_in[4];
    const float* Wfc   = (const float*)d_in[5];
    const float* bfc   = (const float*)d_in[6];
    float* out = (float*)d_out;
    float* ws  = (float*)d_ws;

    kprep<<<73, 256, 0, stream>>>(Wb, We, be, Wfc, bfc, ws);
    kpe<<<368, 256, 0, stream>>>(eos, ws);
    dim3 g(32, 23);
    kmain<<<g, 256, 0, stream>>>(table, ws, out);
}